// Round 10
// baseline (80.126 us; speedup 1.0000x reference)
//
#include <hip/hip_runtime.h>
#include <math.h>

#define NT 100       // NUM_TOPICS
#define VOCAB 8192
#define TOPN 20
#define CAP 4096
#define N2B 20       // node-2 blocks
#define TPB 5        // topics per node-2 block (N2B*TPB == NT)

// ============ node 1: topk + W-gather + per-topic stats (100 x 1024) ============
__global__ __launch_bounds__(1024) void topk_gather_kernel(
    const float* __restrict__ beta,
    const float* __restrict__ W,
    int*   __restrict__ top_idx,   // [NT][TOPN]
    float* __restrict__ M,         // [NT][VOCAB]
    float* __restrict__ stats,     // [NT][8] = {mn,mx,A,B,rmax,rsum,-,-}
    float* __restrict__ out)
{
    const int k = blockIdx.x;
    const int t = threadIdx.x;
    if (k == 0 && t == 0) *out = 0.f;

    __shared__ float sred[16];
    __shared__ int   sredi[16];
    __shared__ int   s_base;
    __shared__ float cu[CAP];                // candidate values (16 KB)
    __shared__ unsigned short ci[CAP];       // candidate indices (8 KB)
    __shared__ float s_winv[TOPN];
    __shared__ int   s_wini[TOPN];
    __shared__ float s_ps;
    __shared__ float s_rsum;
    __shared__ int   sIdx[TOPN];
    __shared__ float sP[TOPN];
    __shared__ float sA[16], sB[16], sC[16], sD[16];

    const float* row = beta + (size_t)k * VOCAB;
    float4 r0 = *reinterpret_cast<const float4*>(row + (size_t)t * 4);
    float4 r1 = *reinterpret_cast<const float4*>(row + (size_t)(1024 + t) * 4);

    // ---- block max ----
    float mx = fmaxf(fmaxf(fmaxf(r0.x, r0.y), fmaxf(r0.z, r0.w)),
                     fmaxf(fmaxf(r1.x, r1.y), fmaxf(r1.z, r1.w)));
#pragma unroll
    for (int off = 32; off >= 1; off >>= 1) mx = fmaxf(mx, __shfl_down(mx, off));
    if ((t & 63) == 0) sred[t >> 6] = mx;
    __syncthreads();
    float rowmax = sred[0];
#pragma unroll
    for (int w = 1; w < 16; ++w) rowmax = fmaxf(rowmax, sred[w]);
    __syncthreads();

    // ---- threshold with count(>=T) >= TOPN ----
    float T = rowmax - 2.0f;
    for (int guard = 0; guard < 64; ++guard) {
        int c = 0;
        c += (r0.x >= T) + (r0.y >= T) + (r0.z >= T) + (r0.w >= T);
        c += (r1.x >= T) + (r1.y >= T) + (r1.z >= T) + (r1.w >= T);
#pragma unroll
        for (int off = 32; off >= 1; off >>= 1) c += __shfl_down(c, off);
        if ((t & 63) == 0) sredi[t >> 6] = c;
        __syncthreads();
        int cnt = 0;
#pragma unroll
        for (int w = 0; w < 16; ++w) cnt += sredi[w];
        if (cnt >= TOPN) break;               // uniform decision
        T -= 0.5f;
        __syncthreads();
    }
    if (t == 0) s_base = 0;
    __syncthreads();

    // ---- ballot-compact candidates ----
#pragma unroll
    for (int i = 0; i < 2; ++i) {
        const float4 rr = (i == 0) ? r0 : r1;
#pragma unroll
        for (int e = 0; e < 4; ++e) {
            const float v = (&rr.x)[e];
            const int idx = (i * 1024 + t) * 4 + e;
            const bool pr = (v >= T);
            const unsigned long long mask = __ballot(pr);
            const int lane = t & 63;
            const int pre = __popcll(mask & ((1ull << lane) - 1ull));
            int base = 0;
            if (lane == 0) base = atomicAdd(&s_base, __popcll(mask));
            base = __shfl(base, 0);
            if (pr) {
                const int p = base + pre;
                if (p < CAP) { cu[p] = v; ci[p] = (unsigned short)idx; }
            }
        }
    }
    __syncthreads();
    const int ncand = min(s_base, CAP);

    // ---- 20 extractions (single wave) ----
    if (t < 64) {
        for (int it = 0; it < TOPN; ++it) {
            float bv = -INFINITY; int bp = -1;
            for (int p = t; p < ncand; p += 64) {
                const float v = cu[p];
                if (v > bv) { bv = v; bp = p; }
            }
#pragma unroll
            for (int off = 32; off >= 1; off >>= 1) {
                const float ov = __shfl_down(bv, off);
                const int   op = __shfl_down(bp, off);
                if (ov > bv) { bv = ov; bp = op; }
            }
            bp = __shfl(bp, 0);
            bv = __shfl(bv, 0);
            if (t == 0) { s_winv[it] = bv; s_wini[it] = ci[bp]; }
            cu[bp] = -INFINITY;
        }
    }
    __syncthreads();

    if (t == 0) {
        float ps = 0.f;
#pragma unroll
        for (int j = 0; j < TOPN; ++j) ps += expf(s_winv[j] - rowmax);
        s_ps = ps;
    }
    __syncthreads();

    // ---- full-row sumexp (before gather; needed for w4) ----
    float se = expf(r0.x - rowmax) + expf(r0.y - rowmax)
             + expf(r0.z - rowmax) + expf(r0.w - rowmax)
             + expf(r1.x - rowmax) + expf(r1.y - rowmax)
             + expf(r1.z - rowmax) + expf(r1.w - rowmax);
#pragma unroll
    for (int off = 32; off >= 1; off >>= 1) se += __shfl_down(se, off);
    if ((t & 63) == 0) sred[t >> 6] = se;
    __syncthreads();
    if (t == 0) {
        float s = 0.f;
#pragma unroll
        for (int w = 0; w < 16; ++w) s += sred[w];
        s_rsum = s;
    }
    if (t < TOPN) {
        sIdx[t] = s_wini[t];
        sP[t]   = expf(s_winv[t] - rowmax) / s_ps;
        top_idx[k * TOPN + t] = s_wini[t];
    }
    __syncthreads();

    const float rsum = s_rsum;
    const float rinv = 1.0f / rsum;

    int   idx_r[TOPN];
    float p_r[TOPN];
#pragma unroll
    for (int j = 0; j < TOPN; ++j) { idx_r[j] = sIdx[j]; p_r[j] = sP[j]; }

    // ---- gather: M = p @ W, stats {mn,mx,A,B} (beta from registers) ----
    float mn = INFINITY, mxv = -INFINITY, Asum = 0.f, Bsum = 0.f;
#pragma unroll
    for (int seg = 0; seg < 2; ++seg) {
        const int col = seg * 4096 + t * 4;
        float4 m = make_float4(0.f, 0.f, 0.f, 0.f);
#pragma unroll
        for (int j = 0; j < TOPN; ++j) {
            const float4 w = *reinterpret_cast<const float4*>(W + (size_t)idx_r[j] * VOCAB + col);
            const float pj = p_r[j];
            m.x += pj * w.x; m.y += pj * w.y; m.z += pj * w.z; m.w += pj * w.w;
        }
        *reinterpret_cast<float4*>(M + (size_t)k * VOCAB + col) = m;
        mn  = fminf(mn,  fminf(fminf(m.x, m.y), fminf(m.z, m.w)));
        mxv = fmaxf(mxv, fmaxf(fmaxf(m.x, m.y), fmaxf(m.z, m.w)));

        const float4 bb = (seg == 0) ? r0 : r1;
        float4 w4;
        w4.x = expf(bb.x - rowmax) * rinv;  w4.x = 100.f * w4.x * w4.x;
        w4.y = expf(bb.y - rowmax) * rinv;  w4.y = 100.f * w4.y * w4.y;
        w4.z = expf(bb.z - rowmax) * rinv;  w4.z = 100.f * w4.z * w4.z;
        w4.w = expf(bb.w - rowmax) * rinv;  w4.w = 100.f * w4.w * w4.w;
        Asum += w4.x + w4.y + w4.z + w4.w;
        Bsum += w4.x * m.x + w4.y * m.y + w4.z * m.z + w4.w * m.w;
    }

#pragma unroll
    for (int off = 32; off >= 1; off >>= 1) {
        mn   = fminf(mn,  __shfl_down(mn,  off));
        mxv  = fmaxf(mxv, __shfl_down(mxv, off));
        Asum += __shfl_down(Asum, off);
        Bsum += __shfl_down(Bsum, off);
    }
    if ((t & 63) == 0) {
        const int w = t >> 6;
        sA[w] = mn; sB[w] = mxv; sC[w] = Asum; sD[w] = Bsum;
    }
    __syncthreads();
    if (t == 0) {
        float a = sA[0], b = sB[0], A = 0.f, B = 0.f;
#pragma unroll
        for (int w = 0; w < 16; ++w) {
            a = fminf(a, sA[w]); b = fmaxf(b, sB[w]);
            A += sC[w]; B += sD[w];
        }
        float* s8 = stats + k * 8;
        s8[0] = a; s8[1] = b; s8[2] = A; s8[3] = B; s8[4] = rowmax; s8[5] = rsum;
    }
}

// ============ node 2: Md-masked pos sums + finalize (20 x 512) ============
__global__ __launch_bounds__(512) void mdsum_kernel(
    const float* __restrict__ beta,
    const float* __restrict__ M,
    const int*   __restrict__ top_idx,
    const float* __restrict__ stats,
    const int*   __restrict__ epoch,
    float* __restrict__ out)
{
    const int b = blockIdx.x;
    const int t = threadIdx.x;

    __shared__ int cnt[VOCAB];               // 32 KB global top-k histogram
    __shared__ unsigned own[VOCAB / 32];     // 1 KB per-topic bitmap
    __shared__ float sred[8];
    __shared__ float s_block;

    if (t == 0) s_block = 0.f;
#pragma unroll
    for (int i = 0; i < VOCAB / 512; ++i) cnt[i * 512 + t] = 0;
    __syncthreads();
    for (int e = t; e < NT * TOPN; e += 512) atomicAdd(&cnt[top_idx[e]], 1);
    __syncthreads();

    for (int kk = 0; kk < TPB; ++kk) {
        const int k = b * TPB + kk;
        if (t < VOCAB / 32) own[t] = 0u;     // 256 words
        __syncthreads();
        if (t < TOPN) {
            const int v = top_idx[k * TOPN + t];
            atomicOr(&own[v >> 5], 1u << (v & 31));
        }
        __syncthreads();

        const float* s8 = stats + k * 8;
        const float mn   = s8[0];
        const float inv  = 1.0f / (s8[1] - mn);
        const float rmax = s8[4];
        const float rinv = 1.0f / s8[5];

        float pos = 0.f;
#pragma unroll
        for (int seg = 0; seg < VOCAB / 512; ++seg) {
            const int v = seg * 512 + t;
            const int ob = (own[v >> 5] >> (v & 31)) & 1;
            if (cnt[v] - ob > 0) {
                const float mv = M[(size_t)k * VOCAB + v];
                float w4 = expf(beta[(size_t)k * VOCAB + v] - rmax) * rinv;
                w4 = 100.f * w4 * w4;
                pos += w4 * (1.0f - (mv - mn) * inv);
            }
        }
#pragma unroll
        for (int off = 32; off >= 1; off >>= 1) pos += __shfl_down(pos, off);
        if ((t & 63) == 0) sred[t >> 6] = pos;
        __syncthreads();
        if (t == 0) {
            float p = 0.f;
#pragma unroll
            for (int w = 0; w < 8; ++w) p += sred[w];
            const float A = s8[2], B = s8[3];
            const float sum_all = A - inv * (B - mn * A);
            s_block += 0.6f * sum_all + 0.8f * p;   // = 2*(0.3*all + 0.4*pos)
        }
        __syncthreads();
    }

    if (t == 0) {
        const int e = *epoch;
        const float la = (e < 100) ? (float)e : 100.0f;   // lambda_a_delta = 1
        atomicAdd(out, la * s_block);
    }
}

extern "C" void kernel_launch(void* const* d_in, const int* in_sizes, int n_in,
                              void* d_out, int out_size, void* d_ws, size_t ws_size,
                              hipStream_t stream)
{
    (void)in_sizes; (void)n_in; (void)out_size; (void)ws_size;
    const float* beta  = (const float*)d_in[0];
    const float* W     = (const float*)d_in[1];
    const int*   epoch = (const int*)d_in[2];
    float* out = (float*)d_out;

    char* ws = (char*)d_ws;
    int*   top_idx = (int*)ws;    ws += NT * TOPN * sizeof(int);
    float* stats   = (float*)ws;  ws += NT * 8 * sizeof(float);
    ws = (char*)(((size_t)ws + 255) & ~(size_t)255);
    float* M       = (float*)ws;  ws += (size_t)NT * VOCAB * sizeof(float);

    topk_gather_kernel<<<NT, 1024, 0, stream>>>(beta, W, top_idx, M, stats, out);
    mdsum_kernel<<<N2B, 512, 0, stream>>>(beta, M, top_idx, stats, epoch, out);
}

// Round 11
// 63.904 us; speedup vs baseline: 1.2538x; 1.2538x over previous
//
#include <hip/hip_runtime.h>
#include <math.h>

#define NT 100       // NUM_TOPICS
#define VOCAB 8192
#define TOPN 20
#define CHUNKS 8
#define CCOLS 1024               // VOCAB / CHUNKS
#define NB (NT * CHUNKS)         // 800 fused blocks
#define CAP 4096

// ---------------- per-topic top-20 via threshold filter (1024 thr) ----------------
__global__ __launch_bounds__(1024) void topk_kernel(
    const float* __restrict__ beta,
    int*   __restrict__ top_idx,   // [NT][TOPN]
    float* __restrict__ top_p,     // [NT][TOPN]
    float* __restrict__ rowstats)  // [NT][2] = {rowmax, full sumexp}
{
    const int k = blockIdx.x;
    const int t = threadIdx.x;

    __shared__ float sred[16];
    __shared__ int   sredi[16];
    __shared__ int   s_base;
    __shared__ float cu[CAP];                // 16 KB candidate values
    __shared__ unsigned short ci[CAP];       // 8 KB candidate indices
    __shared__ float s_winv[TOPN];
    __shared__ int   s_wini[TOPN];
    __shared__ float s_ps;

    const float* row = beta + (size_t)k * VOCAB;

    float4 r0 = *reinterpret_cast<const float4*>(row + (size_t)t * 4);
    float4 r1 = *reinterpret_cast<const float4*>(row + (size_t)(1024 + t) * 4);

    float mx = fmaxf(fmaxf(fmaxf(r0.x, r0.y), fmaxf(r0.z, r0.w)),
                     fmaxf(fmaxf(r1.x, r1.y), fmaxf(r1.z, r1.w)));
#pragma unroll
    for (int off = 32; off >= 1; off >>= 1) mx = fmaxf(mx, __shfl_down(mx, off));
    if ((t & 63) == 0) sred[t >> 6] = mx;
    __syncthreads();
    float rowmax = sred[0];
#pragma unroll
    for (int w = 1; w < 16; ++w) rowmax = fmaxf(rowmax, sred[w]);
    __syncthreads();

    // threshold T with count(>=T) >= TOPN (1 iter typical for N(0,1))
    float T = rowmax - 2.0f;
    for (int guard = 0; guard < 64; ++guard) {
        int c = 0;
        c += (r0.x >= T) + (r0.y >= T) + (r0.z >= T) + (r0.w >= T);
        c += (r1.x >= T) + (r1.y >= T) + (r1.z >= T) + (r1.w >= T);
#pragma unroll
        for (int off = 32; off >= 1; off >>= 1) c += __shfl_down(c, off);
        if ((t & 63) == 0) sredi[t >> 6] = c;
        __syncthreads();
        int cnt = 0;
#pragma unroll
        for (int w = 0; w < 16; ++w) cnt += sredi[w];
        if (cnt >= TOPN) break;               // uniform decision
        T -= 0.5f;
        __syncthreads();
    }
    if (t == 0) s_base = 0;
    __syncthreads();

    // ballot-compact candidates from registers
#pragma unroll
    for (int i = 0; i < 2; ++i) {
        const float4 rr = (i == 0) ? r0 : r1;
#pragma unroll
        for (int e = 0; e < 4; ++e) {
            const float v = (&rr.x)[e];
            const int idx = (i * 1024 + t) * 4 + e;
            const bool pr = (v >= T);
            const unsigned long long mask = __ballot(pr);
            const int lane = t & 63;
            const int pre = __popcll(mask & ((1ull << lane) - 1ull));
            int base = 0;
            if (lane == 0) base = atomicAdd(&s_base, __popcll(mask));
            base = __shfl(base, 0);
            if (pr) {
                const int p = base + pre;
                if (p < CAP) { cu[p] = v; ci[p] = (unsigned short)idx; }
            }
        }
    }
    __syncthreads();
    const int ncand = min(s_base, CAP);

    // 20 extractions, single wave over candidate list
    if (t < 64) {
        for (int it = 0; it < TOPN; ++it) {
            float bv = -INFINITY; int bp = -1;
            for (int p = t; p < ncand; p += 64) {
                const float v = cu[p];
                if (v > bv) { bv = v; bp = p; }
            }
#pragma unroll
            for (int off = 32; off >= 1; off >>= 1) {
                const float ov = __shfl_down(bv, off);
                const int   op = __shfl_down(bp, off);
                if (ov > bv) { bv = ov; bp = op; }
            }
            bp = __shfl(bp, 0);
            bv = __shfl(bv, 0);
            if (t == 0) { s_winv[it] = bv; s_wini[it] = ci[bp]; }
            cu[bp] = -INFINITY;   // uniform same-addr write by the wave
        }
    }
    __syncthreads();

    if (t == 0) {
        float ps = 0.f;
#pragma unroll
        for (int j = 0; j < TOPN; ++j) ps += expf(s_winv[j] - rowmax);
        s_ps = ps;
    }
    __syncthreads();
    if (t < TOPN) {
        top_idx[k * TOPN + t] = s_wini[t];
        top_p[k * TOPN + t]   = expf(s_winv[t] - rowmax) / s_ps;
    }

    // full-row sumexp from registers
    float se = expf(r0.x - rowmax) + expf(r0.y - rowmax)
             + expf(r0.z - rowmax) + expf(r0.w - rowmax)
             + expf(r1.x - rowmax) + expf(r1.y - rowmax)
             + expf(r1.z - rowmax) + expf(r1.w - rowmax);
#pragma unroll
    for (int off = 32; off >= 1; off >>= 1) se += __shfl_down(se, off);
    if ((t & 63) == 0) sred[t >> 6] = se;
    __syncthreads();
    if (t == 0) {
        float s = 0.f;
#pragma unroll
        for (int w = 0; w < 16; ++w) s += sred[w];
        rowstats[2 * k + 0] = rowmax;
        rowstats[2 * k + 1] = s;
    }
}

// -------- fused gather + loss partials (800 x 256, loads-first) --------
// NOTE: pure function of (beta,W,top_idx,top_p,rowstats) -> part6.
// Launched TWICE this round to measure its standalone duration via dur delta.
__global__ __launch_bounds__(256) void fused_kernel(
    const float* __restrict__ beta,
    const float* __restrict__ W,
    const int*   __restrict__ top_idx,
    const float* __restrict__ top_p,
    const float* __restrict__ rowstats,
    float* __restrict__ part6)    // [NB][6] = {min,max,Apos,Bpos,Aneg,Bneg}
{
    const int b = blockIdx.x;
    const int k = b / CHUNKS;
    const int c = b % CHUNKS;
    const int t = threadIdx.x;

    __shared__ int   sIdx[TOPN];
    __shared__ float sP[TOPN];
    __shared__ int   cnt[CCOLS];             // 4 KB chunk histogram
    __shared__ float sA[4], sB[4], sC[4], sD[4], sE[4], sF[4];

    if (t < TOPN) { sIdx[t] = top_idx[k * TOPN + t]; sP[t] = top_p[k * TOPN + t]; }
#pragma unroll
    for (int i = 0; i < CCOLS / 256; ++i) cnt[i * 256 + t] = 0;
    __syncthreads();

    int   idx_r[TOPN];
    float p_r[TOPN];
#pragma unroll
    for (int j = 0; j < TOPN; ++j) { idx_r[j] = sIdx[j]; p_r[j] = sP[j]; }

    // ---- issue all W loads + beta load FIRST (independent of histogram) ----
    const int lo  = c * CCOLS;
    const int col = lo + t * 4;
    float4 w_r[TOPN];
#pragma unroll
    for (int j = 0; j < TOPN; ++j)
        w_r[j] = *reinterpret_cast<const float4*>(W + (size_t)idx_r[j] * VOCAB + col);
    const float4 bv = *reinterpret_cast<const float4*>(beta + (size_t)k * VOCAB + col);

    // ---- histogram over all topics' top-20 (unrolled) ----
#pragma unroll 8
    for (int e = t; e < NT * TOPN; e += 256) {
        const int v = top_idx[e] - lo;
        if ((unsigned)v < (unsigned)CCOLS) atomicAdd(&cnt[v], 1);
    }
    __syncthreads();
    if (t < TOPN) {                          // remove own topic
        const int v = sIdx[t] - lo;
        if ((unsigned)v < (unsigned)CCOLS) atomicSub(&cnt[v], 1);
    }

    // ---- consume: M, min/max, loss weights ----
    float4 m = make_float4(0.f, 0.f, 0.f, 0.f);
#pragma unroll
    for (int j = 0; j < TOPN; ++j) {
        const float pj = p_r[j];
        m.x += pj * w_r[j].x; m.y += pj * w_r[j].y;
        m.z += pj * w_r[j].z; m.w += pj * w_r[j].w;
    }

    float mn  = fminf(fminf(m.x, m.y), fminf(m.z, m.w));
    float mxv = fmaxf(fmaxf(m.x, m.y), fmaxf(m.z, m.w));

    const float rmax = rowstats[2 * k + 0];
    const float rinv = 1.0f / rowstats[2 * k + 1];
    float4 w4;
    w4.x = expf(bv.x - rmax) * rinv;  w4.x = 100.f * w4.x * w4.x;
    w4.y = expf(bv.y - rmax) * rinv;  w4.y = 100.f * w4.y * w4.y;
    w4.z = expf(bv.z - rmax) * rinv;  w4.z = 100.f * w4.z * w4.z;
    w4.w = expf(bv.w - rmax) * rinv;  w4.w = 100.f * w4.w * w4.w;

    __syncthreads();                         // cnt final

    float Apos = 0.f, Bpos = 0.f, Aneg = 0.f, Bneg = 0.f;
    {
        const int lc = t * 4;
        if (cnt[lc + 0] > 0) { Apos += w4.x; Bpos += w4.x * m.x; } else { Aneg += w4.x; Bneg += w4.x * m.x; }
        if (cnt[lc + 1] > 0) { Apos += w4.y; Bpos += w4.y * m.y; } else { Aneg += w4.y; Bneg += w4.y * m.y; }
        if (cnt[lc + 2] > 0) { Apos += w4.z; Bpos += w4.z * m.z; } else { Aneg += w4.z; Bneg += w4.z * m.z; }
        if (cnt[lc + 3] > 0) { Apos += w4.w; Bpos += w4.w * m.w; } else { Aneg += w4.w; Bneg += w4.w * m.w; }
    }

#pragma unroll
    for (int off = 32; off >= 1; off >>= 1) {
        mn   = fminf(mn,  __shfl_down(mn,  off));
        mxv  = fmaxf(mxv, __shfl_down(mxv, off));
        Apos += __shfl_down(Apos, off);
        Bpos += __shfl_down(Bpos, off);
        Aneg += __shfl_down(Aneg, off);
        Bneg += __shfl_down(Bneg, off);
    }
    if ((t & 63) == 0) {
        const int w = t >> 6;
        sA[w] = mn; sB[w] = mxv; sC[w] = Apos; sD[w] = Bpos; sE[w] = Aneg; sF[w] = Bneg;
    }
    __syncthreads();
    if (t == 0) {
        part6[b * 6 + 0] = fminf(fminf(sA[0], sA[1]), fminf(sA[2], sA[3]));
        part6[b * 6 + 1] = fmaxf(fmaxf(sB[0], sB[1]), fmaxf(sB[2], sB[3]));
        part6[b * 6 + 2] = sC[0] + sC[1] + sC[2] + sC[3];
        part6[b * 6 + 3] = sD[0] + sD[1] + sD[2] + sD[3];
        part6[b * 6 + 4] = sE[0] + sE[1] + sE[2] + sE[3];
        part6[b * 6 + 5] = sF[0] + sF[1] + sF[2] + sF[3];
    }
}

// ---------------- deterministic finalize ----------------
__global__ __launch_bounds__(128) void finalize_kernel(
    const float* __restrict__ part6,
    const int*   __restrict__ epoch,
    float* __restrict__ out)
{
    const int t = threadIdx.x;
    __shared__ float sp[128], sn[128];
    float pos = 0.f, neg = 0.f;
    if (t < NT) {
        float mn = INFINITY, mxv = -INFINITY;
        float Ap = 0.f, Bp = 0.f, An = 0.f, Bn = 0.f;
        for (int cc = 0; cc < CHUNKS; ++cc) {
            const float* p6 = part6 + (size_t)(t * CHUNKS + cc) * 6;
            mn  = fminf(mn,  p6[0]);
            mxv = fmaxf(mxv, p6[1]);
            Ap += p6[2]; Bp += p6[3]; An += p6[4]; Bn += p6[5];
        }
        const float inv = 1.0f / (mxv - mn);
        pos = Ap - inv * (Bp - mn * Ap);      // sum w*(1-(M-mn)*inv)
        neg = An - inv * (Bn - mn * An);
    }
    sp[t] = pos; sn[t] = neg;
    __syncthreads();
    if (t == 0) {
        float P = 0.f, N = 0.f;
        for (int i = 0; i < NT; ++i) { P += sp[i]; N += sn[i]; }
        const float total = (P * 0.7f + N * 0.3f) * 2.0f;
        const int e = *epoch;
        const float la = (e < 100) ? (float)e : 100.0f;   // lambda_a_delta = 1
        *out = la * total;
    }
}

extern "C" void kernel_launch(void* const* d_in, const int* in_sizes, int n_in,
                              void* d_out, int out_size, void* d_ws, size_t ws_size,
                              hipStream_t stream)
{
    (void)in_sizes; (void)n_in; (void)out_size; (void)ws_size;
    const float* beta  = (const float*)d_in[0];
    const float* W     = (const float*)d_in[1];
    const int*   epoch = (const int*)d_in[2];
    float* out = (float*)d_out;

    char* ws = (char*)d_ws;
    int*   top_idx  = (int*)ws;    ws += NT * TOPN * sizeof(int);
    float* top_p    = (float*)ws;  ws += NT * TOPN * sizeof(float);
    float* rowstats = (float*)ws;  ws += NT * 2 * sizeof(float);
    float* part6    = (float*)ws;  ws += NB * 6 * sizeof(float);

    topk_kernel<<<NT, 1024, 0, stream>>>(beta, top_idx, top_p, rowstats);
    // fused launched twice (idempotent): dur delta vs R8 pins its standalone cost
    fused_kernel<<<NB, 256, 0, stream>>>(beta, W, top_idx, top_p, rowstats, part6);
    fused_kernel<<<NB, 256, 0, stream>>>(beta, W, top_idx, top_p, rowstats, part6);
    finalize_kernel<<<1, 128, 0, stream>>>(part6, epoch, out);
}

// Round 12
// 49.179 us; speedup vs baseline: 1.6293x; 1.2994x over previous
//
#include <hip/hip_runtime.h>
#include <math.h>

#define NT 100       // NUM_TOPICS
#define VOCAB 8192
#define TOPN 20
#define NSL 8        // slices per topic
#define SCOLS 1024   // cols per slice
#define SCAP 128     // candidate slots per slice (block-owned, no atomics across blocks)
#define CHUNKS 8
#define CCOLS 1024
#define NB (NT * CHUNKS)         // 800 fused blocks

// ---------- node 1: per-(topic,slice) stats + threshold candidate dump ----------
__global__ __launch_bounds__(256) void slice_kernel(
    const float* __restrict__ beta,
    float* __restrict__ cand_val,   // [NT*NSL][SCAP]
    int*   __restrict__ cand_idx,   // [NT*NSL][SCAP]
    int*   __restrict__ sl_cnt,     // [NT*NSL]
    float* __restrict__ sl_max,     // [NT*NSL]
    float* __restrict__ sl_sum)     // [NT*NSL]
{
    const int b = blockIdx.x;
    const int t = threadIdx.x;
    const int k = b / NSL;
    const int s = b % NSL;
    const int col0 = s * SCOLS;

    __shared__ float sred[4];
    __shared__ int   sredi[4];
    __shared__ int   s_cnt;

    const float4 v = *reinterpret_cast<const float4*>(
        beta + (size_t)k * VOCAB + col0 + t * 4);

    // slice max
    float mx = fmaxf(fmaxf(v.x, v.y), fmaxf(v.z, v.w));
#pragma unroll
    for (int off = 32; off >= 1; off >>= 1) mx = fmaxf(mx, __shfl_down(mx, off));
    if ((t & 63) == 0) sred[t >> 6] = mx;
    __syncthreads();
    const float smax = fmaxf(fmaxf(sred[0], sred[1]), fmaxf(sred[2], sred[3]));
    __syncthreads();

    // slice sumexp (local max)
    float se = expf(v.x - smax) + expf(v.y - smax) + expf(v.z - smax) + expf(v.w - smax);
#pragma unroll
    for (int off = 32; off >= 1; off >>= 1) se += __shfl_down(se, off);
    if ((t & 63) == 0) sred[t >> 6] = se;
    __syncthreads();
    const float ssum = sred[0] + sred[1] + sred[2] + sred[3];
    __syncthreads();

    // threshold with slice count >= TOPN (guarantees slice top-20 is included)
    float T = smax - 1.5f;
    for (int g = 0; g < 8; ++g) {
        int c = ((v.x >= T) ? 1 : 0) + ((v.y >= T) ? 1 : 0)
              + ((v.z >= T) ? 1 : 0) + ((v.w >= T) ? 1 : 0);
#pragma unroll
        for (int off = 32; off >= 1; off >>= 1) c += __shfl_down(c, off);
        if ((t & 63) == 0) sredi[t >> 6] = c;
        __syncthreads();
        const int cnt = sredi[0] + sredi[1] + sredi[2] + sredi[3];
        if (cnt >= TOPN) break;              // uniform decision
        T -= 0.4f;
        __syncthreads();
    }
    if (t == 0) s_cnt = 0;
    __syncthreads();

    // ballot-compact candidates (val + global col idx) into block-owned region
#pragma unroll
    for (int e = 0; e < 4; ++e) {
        const float val = (&v.x)[e];
        const bool  pr  = (val >= T);
        const unsigned long long mask = __ballot(pr);
        const int lane = t & 63;
        const int pre  = __popcll(mask & ((1ull << lane) - 1ull));
        int base = 0;
        if (lane == 0) base = atomicAdd(&s_cnt, __popcll(mask));
        base = __shfl(base, 0);
        if (pr) {
            const int p = base + pre;
            if (p < SCAP) {
                cand_val[(size_t)b * SCAP + p] = val;
                cand_idx[(size_t)b * SCAP + p] = col0 + t * 4 + e;
            }
        }
    }
    __syncthreads();
    if (t == 0) {
        sl_cnt[b] = min(s_cnt, SCAP);
        sl_max[b] = smax;
        sl_sum[b] = ssum;
    }
}

// ---------- node 2: per-topic merge -> top-20, softmax stats ----------
__global__ __launch_bounds__(256) void merge_kernel(
    const float* __restrict__ cand_val,
    const int*   __restrict__ cand_idx,
    const int*   __restrict__ sl_cnt,
    const float* __restrict__ sl_max,
    const float* __restrict__ sl_sum,
    int*   __restrict__ top_idx,    // [NT][TOPN]
    float* __restrict__ top_p,      // [NT][TOPN]
    float* __restrict__ rowstats)   // [NT][2] = {rowmax, full sumexp}
{
    const int k = blockIdx.x;
    const int t = threadIdx.x;

    __shared__ int   scnt[NSL];
    __shared__ int   soff[NSL + 1];
    __shared__ float smaxs[NSL], ssums[NSL];
    __shared__ float cval[NSL * SCAP];       // 4 KB
    __shared__ int   cidx[NSL * SCAP];       // 4 KB
    __shared__ float s_winv[TOPN];
    __shared__ int   s_wini[TOPN];
    __shared__ float s_ps, s_rowmax;

    if (t < NSL) {
        scnt[t]  = sl_cnt[k * NSL + t];
        smaxs[t] = sl_max[k * NSL + t];
        ssums[t] = sl_sum[k * NSL + t];
    }
    __syncthreads();
    if (t == 0) {
        int o = 0;
#pragma unroll
        for (int s = 0; s < NSL; ++s) { soff[s] = o; o += scnt[s]; }
        soff[NSL] = o;
        float rm = smaxs[0];
#pragma unroll
        for (int s = 1; s < NSL; ++s) rm = fmaxf(rm, smaxs[s]);
        s_rowmax = rm;
    }
    __syncthreads();
    const int total = soff[NSL];
    const float rowmax = s_rowmax;

    // gather candidates into contiguous LDS
#pragma unroll
    for (int s = 0; s < NSL; ++s) {
        const int n = scnt[s], o = soff[s];
        for (int p = t; p < n; p += 256) {
            cval[o + p] = cand_val[(size_t)(k * NSL + s) * SCAP + p];
            cidx[o + p] = cand_idx[(size_t)(k * NSL + s) * SCAP + p];
        }
    }
    __syncthreads();

    // 20 extractions, single wave
    if (t < 64) {
        for (int it = 0; it < TOPN; ++it) {
            float bv = -INFINITY; int bp = -1;
            for (int p = t; p < total; p += 64) {
                const float vv = cval[p];
                if (vv > bv) { bv = vv; bp = p; }
            }
#pragma unroll
            for (int off = 32; off >= 1; off >>= 1) {
                const float ov = __shfl_down(bv, off);
                const int   op = __shfl_down(bp, off);
                if (ov > bv) { bv = ov; bp = op; }
            }
            bp = __shfl(bp, 0);
            bv = __shfl(bv, 0);
            if (t == 0) { s_winv[it] = bv; s_wini[it] = cidx[bp]; }
            cval[bp] = -INFINITY;            // uniform same-addr write
        }
    }
    __syncthreads();

    if (t == 0) {
        float ps = 0.f;
#pragma unroll
        for (int j = 0; j < TOPN; ++j) ps += expf(s_winv[j] - rowmax);
        s_ps = ps;
        float rs = 0.f;
#pragma unroll
        for (int s = 0; s < NSL; ++s) rs += ssums[s] * expf(smaxs[s] - rowmax);
        rowstats[2 * k + 0] = rowmax;
        rowstats[2 * k + 1] = rs;
    }
    __syncthreads();
    if (t < TOPN) {
        top_idx[k * TOPN + t] = s_wini[t];
        top_p[k * TOPN + t]   = expf(s_winv[t] - rowmax) / s_ps;
    }
}

// -------- node 3: fused gather + loss partials (VERBATIM R8, proven) --------
__global__ __launch_bounds__(256) void fused_kernel(
    const float* __restrict__ beta,
    const float* __restrict__ W,
    const int*   __restrict__ top_idx,
    const float* __restrict__ top_p,
    const float* __restrict__ rowstats,
    float* __restrict__ part6)    // [NB][6] = {min,max,Apos,Bpos,Aneg,Bneg}
{
    const int b = blockIdx.x;
    const int k = b / CHUNKS;
    const int c = b % CHUNKS;
    const int t = threadIdx.x;

    __shared__ int   sIdx[TOPN];
    __shared__ float sP[TOPN];
    __shared__ int   cnt[CCOLS];
    __shared__ float sA[4], sB[4], sC[4], sD[4], sE[4], sF[4];

    if (t < TOPN) { sIdx[t] = top_idx[k * TOPN + t]; sP[t] = top_p[k * TOPN + t]; }
#pragma unroll
    for (int i = 0; i < CCOLS / 256; ++i) cnt[i * 256 + t] = 0;
    __syncthreads();

    int   idx_r[TOPN];
    float p_r[TOPN];
#pragma unroll
    for (int j = 0; j < TOPN; ++j) { idx_r[j] = sIdx[j]; p_r[j] = sP[j]; }

    const int lo  = c * CCOLS;
    const int col = lo + t * 4;
    float4 w_r[TOPN];
#pragma unroll
    for (int j = 0; j < TOPN; ++j)
        w_r[j] = *reinterpret_cast<const float4*>(W + (size_t)idx_r[j] * VOCAB + col);
    const float4 bv = *reinterpret_cast<const float4*>(beta + (size_t)k * VOCAB + col);

#pragma unroll 8
    for (int e = t; e < NT * TOPN; e += 256) {
        const int v = top_idx[e] - lo;
        if ((unsigned)v < (unsigned)CCOLS) atomicAdd(&cnt[v], 1);
    }
    __syncthreads();
    if (t < TOPN) {
        const int v = sIdx[t] - lo;
        if ((unsigned)v < (unsigned)CCOLS) atomicSub(&cnt[v], 1);
    }

    float4 m = make_float4(0.f, 0.f, 0.f, 0.f);
#pragma unroll
    for (int j = 0; j < TOPN; ++j) {
        const float pj = p_r[j];
        m.x += pj * w_r[j].x; m.y += pj * w_r[j].y;
        m.z += pj * w_r[j].z; m.w += pj * w_r[j].w;
    }

    float mn  = fminf(fminf(m.x, m.y), fminf(m.z, m.w));
    float mxv = fmaxf(fmaxf(m.x, m.y), fmaxf(m.z, m.w));

    const float rmax = rowstats[2 * k + 0];
    const float rinv = 1.0f / rowstats[2 * k + 1];
    float4 w4;
    w4.x = expf(bv.x - rmax) * rinv;  w4.x = 100.f * w4.x * w4.x;
    w4.y = expf(bv.y - rmax) * rinv;  w4.y = 100.f * w4.y * w4.y;
    w4.z = expf(bv.z - rmax) * rinv;  w4.z = 100.f * w4.z * w4.z;
    w4.w = expf(bv.w - rmax) * rinv;  w4.w = 100.f * w4.w * w4.w;

    __syncthreads();

    float Apos = 0.f, Bpos = 0.f, Aneg = 0.f, Bneg = 0.f;
    {
        const int lc = t * 4;
        if (cnt[lc + 0] > 0) { Apos += w4.x; Bpos += w4.x * m.x; } else { Aneg += w4.x; Bneg += w4.x * m.x; }
        if (cnt[lc + 1] > 0) { Apos += w4.y; Bpos += w4.y * m.y; } else { Aneg += w4.y; Bneg += w4.y * m.y; }
        if (cnt[lc + 2] > 0) { Apos += w4.z; Bpos += w4.z * m.z; } else { Aneg += w4.z; Bneg += w4.z * m.z; }
        if (cnt[lc + 3] > 0) { Apos += w4.w; Bpos += w4.w * m.w; } else { Aneg += w4.w; Bneg += w4.w * m.w; }
    }

#pragma unroll
    for (int off = 32; off >= 1; off >>= 1) {
        mn   = fminf(mn,  __shfl_down(mn,  off));
        mxv  = fmaxf(mxv, __shfl_down(mxv, off));
        Apos += __shfl_down(Apos, off);
        Bpos += __shfl_down(Bpos, off);
        Aneg += __shfl_down(Aneg, off);
        Bneg += __shfl_down(Bneg, off);
    }
    if ((t & 63) == 0) {
        const int w = t >> 6;
        sA[w] = mn; sB[w] = mxv; sC[w] = Apos; sD[w] = Bpos; sE[w] = Aneg; sF[w] = Bneg;
    }
    __syncthreads();
    if (t == 0) {
        part6[b * 6 + 0] = fminf(fminf(sA[0], sA[1]), fminf(sA[2], sA[3]));
        part6[b * 6 + 1] = fmaxf(fmaxf(sB[0], sB[1]), fmaxf(sB[2], sB[3]));
        part6[b * 6 + 2] = sC[0] + sC[1] + sC[2] + sC[3];
        part6[b * 6 + 3] = sD[0] + sD[1] + sD[2] + sD[3];
        part6[b * 6 + 4] = sE[0] + sE[1] + sE[2] + sE[3];
        part6[b * 6 + 5] = sF[0] + sF[1] + sF[2] + sF[3];
    }
}

// ---------------- node 4: deterministic finalize (VERBATIM R8) ----------------
__global__ __launch_bounds__(128) void finalize_kernel(
    const float* __restrict__ part6,
    const int*   __restrict__ epoch,
    float* __restrict__ out)
{
    const int t = threadIdx.x;
    __shared__ float sp[128], sn[128];
    float pos = 0.f, neg = 0.f;
    if (t < NT) {
        float mn = INFINITY, mxv = -INFINITY;
        float Ap = 0.f, Bp = 0.f, An = 0.f, Bn = 0.f;
        for (int cc = 0; cc < CHUNKS; ++cc) {
            const float* p6 = part6 + (size_t)(t * CHUNKS + cc) * 6;
            mn  = fminf(mn,  p6[0]);
            mxv = fmaxf(mxv, p6[1]);
            Ap += p6[2]; Bp += p6[3]; An += p6[4]; Bn += p6[5];
        }
        const float inv = 1.0f / (mxv - mn);
        pos = Ap - inv * (Bp - mn * Ap);
        neg = An - inv * (Bn - mn * An);
    }
    sp[t] = pos; sn[t] = neg;
    __syncthreads();
    if (t == 0) {
        float P = 0.f, N = 0.f;
        for (int i = 0; i < NT; ++i) { P += sp[i]; N += sn[i]; }
        const float total = (P * 0.7f + N * 0.3f) * 2.0f;
        const int e = *epoch;
        const float la = (e < 100) ? (float)e : 100.0f;
        *out = la * total;
    }
}

extern "C" void kernel_launch(void* const* d_in, const int* in_sizes, int n_in,
                              void* d_out, int out_size, void* d_ws, size_t ws_size,
                              hipStream_t stream)
{
    (void)in_sizes; (void)n_in; (void)out_size; (void)ws_size;
    const float* beta  = (const float*)d_in[0];
    const float* W     = (const float*)d_in[1];
    const int*   epoch = (const int*)d_in[2];
    float* out = (float*)d_out;

    char* ws = (char*)d_ws;
    float* cand_val = (float*)ws;  ws += (size_t)NT * NSL * SCAP * sizeof(float);
    int*   cand_idx = (int*)ws;    ws += (size_t)NT * NSL * SCAP * sizeof(int);
    int*   sl_cnt   = (int*)ws;    ws += NT * NSL * sizeof(int);
    float* sl_max   = (float*)ws;  ws += NT * NSL * sizeof(float);
    float* sl_sum   = (float*)ws;  ws += NT * NSL * sizeof(float);
    int*   top_idx  = (int*)ws;    ws += NT * TOPN * sizeof(int);
    float* top_p    = (float*)ws;  ws += NT * TOPN * sizeof(float);
    float* rowstats = (float*)ws;  ws += NT * 2 * sizeof(float);
    float* part6    = (float*)ws;  ws += NB * 6 * sizeof(float);

    slice_kernel<<<NT * NSL, 256, 0, stream>>>(beta, cand_val, cand_idx,
                                               sl_cnt, sl_max, sl_sum);
    merge_kernel<<<NT, 256, 0, stream>>>(cand_val, cand_idx, sl_cnt, sl_max, sl_sum,
                                         top_idx, top_p, rowstats);
    fused_kernel<<<NB, 256, 0, stream>>>(beta, W, top_idx, top_p, rowstats, part6);
    finalize_kernel<<<1, 128, 0, stream>>>(part6, epoch, out);
}